// Round 1
// baseline (342.259 us; speedup 1.0000x reference)
//
#include <hip/hip_runtime.h>
#include <stdint.h>

#define B_    16
#define FIN   256
#define FOUT  256
#define FH2   256
#define NMIX  8
#define LAT   512
#define HW    4096
#define MT    32

typedef short bf16x8 __attribute__((ext_vector_type(8)));
typedef float f32x4  __attribute__((ext_vector_type(4)));

// workspace layout (bytes)
#define WS_MIX    0           // [16][8] f32
#define WS_BIAS   1024        // [4][16][256] f32 : in, mid, out, short
#define WS_WIN    131072      // [16][256][256] bf16
#define WS_WMID   2228224     // [16][256][512] bf16 (sin/cos interleaved k')
#define WS_WOUT   6422528     // [16][256][512] bf16 (interleaved)
#define WS_WSHORT 10616832    // [16][256][256] bf16

__device__ __forceinline__ uint16_t f2bf(float f) {
  uint32_t u = __builtin_bit_cast(uint32_t, f);
  u += 0x7fffu + ((u >> 16) & 1u);
  return (uint16_t)(u >> 16);
}
__device__ __forceinline__ uint32_t pack2(float lo, float hi) {
  return (uint32_t)f2bf(lo) | ((uint32_t)f2bf(hi) << 16);
}

// ---------------- kernel A: mix + biases ----------------
__global__ void k_mix_bias(const float* __restrict__ lat,
                           const float* __restrict__ w_dyna,
                           const float* __restrict__ b_dyna,
                           const float* __restrict__ b_in_mix,
                           const float* __restrict__ b_mid_mix,
                           const float* __restrict__ b_out_mix,
                           const float* __restrict__ b_short_mix,
                           float* __restrict__ ws_mix,
                           float* __restrict__ ws_bias) {
  __shared__ float smix[B_ * NMIX];
  const int t = threadIdx.x;
  const int lane = t & 63, wv = t >> 6;
  // 128 dot products of length 512; 32 per wave, lane-parallel over L
  for (int d2 = 0; d2 < 32; d2++) {
    int d = wv * 32 + d2;
    int b = d >> 3, m = d & 7;
    float s = 0.f;
#pragma unroll
    for (int j = 0; j < 8; j++)
      s += lat[b * LAT + j * 64 + lane] * w_dyna[m * LAT + j * 64 + lane];
#pragma unroll
    for (int off = 32; off; off >>= 1) s += __shfl_xor(s, off);
    if (lane == 0) {
      float v = s + b_dyna[m];
      ws_mix[d] = v;
      smix[d] = v;
    }
  }
  __syncthreads();
  const float* banks[4] = {b_in_mix, b_mid_mix, b_out_mix, b_short_mix};
  for (int pos = t; pos < 1024; pos += 256) {
    int bank = pos >> 8, ch = pos & 255;
    const float* bp = banks[bank];
    float v[NMIX];
#pragma unroll
    for (int m = 0; m < NMIX; m++) v[m] = bp[m * 256 + ch];
#pragma unroll
    for (int b = 0; b < B_; b++) {
      float a = 0.f;
#pragma unroll
      for (int m = 0; m < NMIX; m++) a += smix[b * NMIX + m] * v[m];
      ws_bias[(bank * B_ + b) * 256 + ch] = a;
    }
  }
}

// ---------------- kernel B: mixed per-sample bf16 weights ----------------
__global__ void k_weights(const float* __restrict__ k_in_mix,
                          const float* __restrict__ k_mid_mix,
                          const float* __restrict__ k_out_mix,
                          const float* __restrict__ k_short_mix,
                          const float* __restrict__ ws_mix,
                          uint16_t* __restrict__ w_in,
                          uint16_t* __restrict__ w_mid,
                          uint16_t* __restrict__ w_out,
                          uint16_t* __restrict__ w_short) {
  __shared__ float smix[B_ * NMIX];
  const int t = threadIdx.x;
  if (t < B_ * NMIX) smix[t] = ws_mix[t];
  __syncthreads();
  const int idx = blockIdx.x * 256 + t;  // 0..393215
  const float* src;
  uint16_t* dst;
  int sstride, dstride;
  if (idx < 65536) {
    src = k_in_mix + idx; sstride = 65536;
    dst = w_in + idx;     dstride = 65536;
  } else if (idx < 196608) {
    int j = idx - 65536, o = j >> 9, kp = j & 511;
    int i = (kp >> 1) + ((kp & 1) << 8);      // interleaved sin/cos -> source channel
    src = k_mid_mix + o * 512 + i; sstride = 131072;
    dst = w_mid + j;               dstride = 131072;
  } else if (idx < 327680) {
    int j = idx - 196608, o = j >> 9, kp = j & 511;
    int i = (kp >> 1) + ((kp & 1) << 8);
    src = k_out_mix + o * 512 + i; sstride = 131072;
    dst = w_out + j;               dstride = 131072;
  } else {
    int j = idx - 327680;
    src = k_short_mix + j; sstride = 65536;
    dst = w_short + j;     dstride = 65536;
  }
  float v[NMIX];
#pragma unroll
  for (int m = 0; m < NMIX; m++) v[m] = src[m * sstride];
  for (int b = 0; b < B_; b++) {
    float a = 0.f;
#pragma unroll
    for (int m = 0; m < NMIX; m++) a += smix[b * NMIX + m] * v[m];
    dst[b * dstride] = f2bf(a);
  }
}

// ---------------- main fused kernel ----------------
// block = (sample b, 32 spatial cols). 256 thr = 4 waves, each wave owns 4 o-tiles.
// LDS: bufA (32KB) = Xs [32][264] bf16 padded, later H2c [32][512] chunk-xor swizzled.
//      bufB (32KB) = H1c [32][512] chunk-xor swizzled.
__launch_bounds__(256, 2)
__global__ void k_main(const float* __restrict__ x,
                       const float* __restrict__ ws_bias,
                       const uint16_t* __restrict__ w_in,
                       const uint16_t* __restrict__ w_mid,
                       const uint16_t* __restrict__ w_out,
                       const uint16_t* __restrict__ w_short,
                       float* __restrict__ out) {
  __shared__ int4 smem4[65536 / 16];
  char* bufA = (char*)smem4;
  char* bufB = (char*)smem4 + 32768;

  const int t = threadIdx.x;
  const int lane = t & 63;
  const int wv = t >> 6;          // wave 0..3
  const int q = lane >> 4;        // quad 0..3
  const int n = lane & 15;
  const int b = blockIdx.y;
  const int p0 = blockIdx.x * MT;

  // ---- stage X tile -> bufA as bf16, layout Xs[p][i], rowstride 264 elems ----
  {
    const float* xb = x + (size_t)b * FIN * HW + p0;
    const int w = t & 31;
    const int ip = t >> 5;  // 0..7
#pragma unroll
    for (int it = 0; it < 16; it++) {
      int i = 2 * ip + 16 * it;
      float v0 = xb[(size_t)i * HW + w];
      float v1 = xb[(size_t)(i + 1) * HW + w];
      *(uint32_t*)(bufA + w * 528 + i * 2) = pack2(v0, v1);
    }
  }
  __syncthreads();

  // ---- stage 1: h1 = K_in @ X + b_in ; short = K_short @ X + b_short ----
  f32x4 acc_h[4][2], acc_s[4][2];
#pragma unroll
  for (int ots = 0; ots < 4; ots++) {
    int o = (wv * 4 + ots) * 16 + q * 4;
#pragma unroll
    for (int r = 0; r < 4; r++) {
      float vi = ws_bias[(0 * B_ + b) * 256 + o + r];
      float vs = ws_bias[(3 * B_ + b) * 256 + o + r];
      acc_h[ots][0][r] = vi; acc_h[ots][1][r] = vi;
      acc_s[ots][0][r] = vs; acc_s[ots][1][r] = vs;
    }
  }
  {
    const uint16_t* Wi = w_in + (size_t)b * 65536;
    const uint16_t* Ws = w_short + (size_t)b * 65536;
#pragma unroll
    for (int kt = 0; kt < 8; kt++) {
      bf16x8 bf0 = *(const bf16x8*)(bufA + n * 528 + kt * 64 + q * 16);
      bf16x8 bf1 = *(const bf16x8*)(bufA + (16 + n) * 528 + kt * 64 + q * 16);
#pragma unroll
      for (int ots = 0; ots < 4; ots++) {
        int orow = (wv * 4 + ots) * 16 + n;
        bf16x8 ai = *(const bf16x8*)(Wi + orow * 256 + kt * 32 + q * 8);
        bf16x8 as = *(const bf16x8*)(Ws + orow * 256 + kt * 32 + q * 8);
        acc_h[ots][0] = __builtin_amdgcn_mfma_f32_16x16x32_bf16(ai, bf0, acc_h[ots][0], 0, 0, 0);
        acc_h[ots][1] = __builtin_amdgcn_mfma_f32_16x16x32_bf16(ai, bf1, acc_h[ots][1], 0, 0, 0);
        acc_s[ots][0] = __builtin_amdgcn_mfma_f32_16x16x32_bf16(as, bf0, acc_s[ots][0], 0, 0, 0);
        acc_s[ots][1] = __builtin_amdgcn_mfma_f32_16x16x32_bf16(as, bf1, acc_s[ots][1], 0, 0, 0);
      }
    }
  }
  // complex_wave(h1) -> H1c (bufB), k' = 2*o + {0:sin,1:cos}, chunk-xor swizzle
#pragma unroll
  for (int ots = 0; ots < 4; ots++) {
    int ctile = (wv * 4 + ots) * 4 + q;  // 16B chunk index within row
#pragma unroll
    for (int pt = 0; pt < 2; pt++) {
      int p = pt * 16 + n;
      uint32_t u0 = pack2(__sinf(acc_h[ots][pt][0]), __cosf(acc_h[ots][pt][0]));
      uint32_t u1 = pack2(__sinf(acc_h[ots][pt][1]), __cosf(acc_h[ots][pt][1]));
      uint32_t u2 = pack2(__sinf(acc_h[ots][pt][2]), __cosf(acc_h[ots][pt][2]));
      uint32_t u3 = pack2(__sinf(acc_h[ots][pt][3]), __cosf(acc_h[ots][pt][3]));
      *(int4*)(bufB + p * 1024 + ((ctile ^ (p & 7)) * 16)) =
          make_int4((int)u0, (int)u1, (int)u2, (int)u3);
    }
  }
  __syncthreads();

  // ---- stage 2: h2 = K_mid(perm) @ H1c + b_mid ----
  f32x4 acc2[4][2];
#pragma unroll
  for (int ots = 0; ots < 4; ots++) {
    int o = (wv * 4 + ots) * 16 + q * 4;
#pragma unroll
    for (int r = 0; r < 4; r++) {
      float v = ws_bias[(1 * B_ + b) * 256 + o + r];
      acc2[ots][0][r] = v; acc2[ots][1][r] = v;
    }
  }
  {
    const uint16_t* Wm = w_mid + (size_t)b * 131072;
#pragma unroll
    for (int kt = 0; kt < 16; kt++) {
      int sw = ((kt * 4 + q) ^ (n & 7)) * 16;   // (16+n)&7 == n&7
      bf16x8 bf0 = *(const bf16x8*)(bufB + n * 1024 + sw);
      bf16x8 bf1 = *(const bf16x8*)(bufB + (16 + n) * 1024 + sw);
#pragma unroll
      for (int ots = 0; ots < 4; ots++) {
        int orow = (wv * 4 + ots) * 16 + n;
        bf16x8 am = *(const bf16x8*)(Wm + orow * 512 + kt * 32 + q * 8);
        acc2[ots][0] = __builtin_amdgcn_mfma_f32_16x16x32_bf16(am, bf0, acc2[ots][0], 0, 0, 0);
        acc2[ots][1] = __builtin_amdgcn_mfma_f32_16x16x32_bf16(am, bf1, acc2[ots][1], 0, 0, 0);
      }
    }
  }
  __syncthreads();   // everyone done reading H1c & (long ago) Xs
  // complex_wave(h2) -> H2c (bufA), same swizzle
#pragma unroll
  for (int ots = 0; ots < 4; ots++) {
    int ctile = (wv * 4 + ots) * 4 + q;
#pragma unroll
    for (int pt = 0; pt < 2; pt++) {
      int p = pt * 16 + n;
      uint32_t u0 = pack2(__sinf(acc2[ots][pt][0]), __cosf(acc2[ots][pt][0]));
      uint32_t u1 = pack2(__sinf(acc2[ots][pt][1]), __cosf(acc2[ots][pt][1]));
      uint32_t u2 = pack2(__sinf(acc2[ots][pt][2]), __cosf(acc2[ots][pt][2]));
      uint32_t u3 = pack2(__sinf(acc2[ots][pt][3]), __cosf(acc2[ots][pt][3]));
      *(int4*)(bufA + p * 1024 + ((ctile ^ (p & 7)) * 16)) =
          make_int4((int)u0, (int)u1, (int)u2, (int)u3);
    }
  }
  __syncthreads();

  // ---- stage 3: out = K_out(perm) @ H2c + b_out + short ----
  f32x4 acc3[4][2];
#pragma unroll
  for (int ots = 0; ots < 4; ots++) {
    int o = (wv * 4 + ots) * 16 + q * 4;
#pragma unroll
    for (int r = 0; r < 4; r++) {
      float v = ws_bias[(2 * B_ + b) * 256 + o + r];
      acc3[ots][0][r] = acc_s[ots][0][r] + v;
      acc3[ots][1][r] = acc_s[ots][1][r] + v;
    }
  }
  {
    const uint16_t* Wo = w_out + (size_t)b * 131072;
#pragma unroll
    for (int kt = 0; kt < 16; kt++) {
      int sw = ((kt * 4 + q) ^ (n & 7)) * 16;
      bf16x8 bf0 = *(const bf16x8*)(bufA + n * 1024 + sw);
      bf16x8 bf1 = *(const bf16x8*)(bufA + (16 + n) * 1024 + sw);
#pragma unroll
      for (int ots = 0; ots < 4; ots++) {
        int orow = (wv * 4 + ots) * 16 + n;
        bf16x8 ao = *(const bf16x8*)(Wo + orow * 512 + kt * 32 + q * 8);
        acc3[ots][0] = __builtin_amdgcn_mfma_f32_16x16x32_bf16(ao, bf0, acc3[ots][0], 0, 0, 0);
        acc3[ots][1] = __builtin_amdgcn_mfma_f32_16x16x32_bf16(ao, bf1, acc3[ots][1], 0, 0, 0);
      }
    }
  }
  // store
  {
    float* ob = out + (size_t)b * FOUT * HW + p0;
#pragma unroll
    for (int ots = 0; ots < 4; ots++) {
#pragma unroll
      for (int pt = 0; pt < 2; pt++) {
#pragma unroll
        for (int r = 0; r < 4; r++) {
          int o = (wv * 4 + ots) * 16 + q * 4 + r;
          ob[(size_t)o * HW + pt * 16 + n] = acc3[ots][pt][r];
        }
      }
    }
  }
}

extern "C" void kernel_launch(void* const* d_in, const int* in_sizes, int n_in,
                              void* d_out, int out_size, void* d_ws, size_t ws_size,
                              hipStream_t stream) {
  const float* x           = (const float*)d_in[0];
  const float* lat         = (const float*)d_in[1];
  const float* k_in_mix    = (const float*)d_in[2];
  const float* k_mid_mix   = (const float*)d_in[3];
  const float* k_out_mix   = (const float*)d_in[4];
  const float* k_short_mix = (const float*)d_in[5];
  const float* b_in_mix    = (const float*)d_in[6];
  const float* b_mid_mix   = (const float*)d_in[7];
  const float* b_out_mix   = (const float*)d_in[8];
  const float* b_short_mix = (const float*)d_in[9];
  const float* w_dyna      = (const float*)d_in[10];
  const float* b_dyna      = (const float*)d_in[11];

  char* ws = (char*)d_ws;
  float*    ws_mix  = (float*)(ws + WS_MIX);
  float*    ws_bias = (float*)(ws + WS_BIAS);
  uint16_t* w_in    = (uint16_t*)(ws + WS_WIN);
  uint16_t* w_mid   = (uint16_t*)(ws + WS_WMID);
  uint16_t* w_out   = (uint16_t*)(ws + WS_WOUT);
  uint16_t* w_short = (uint16_t*)(ws + WS_WSHORT);
  float* out = (float*)d_out;

  hipLaunchKernelGGL(k_mix_bias, dim3(1), dim3(256), 0, stream,
                     lat, w_dyna, b_dyna, b_in_mix, b_mid_mix, b_out_mix,
                     b_short_mix, ws_mix, ws_bias);
  hipLaunchKernelGGL(k_weights, dim3(1536), dim3(256), 0, stream,
                     k_in_mix, k_mid_mix, k_out_mix, k_short_mix, ws_mix,
                     w_in, w_mid, w_out, w_short);
  hipLaunchKernelGGL(k_main, dim3(128, 16), dim3(256), 0, stream,
                     x, ws_bias, w_in, w_mid, w_out, w_short, out);
}